// Round 7
// baseline (96.796 us; speedup 1.0000x reference)
//
#include <hip/hip_runtime.h>
#include <hip/hip_bf16.h>

#define NN 100000
#define NE 400000
#define S  32
#define B  4096
#define DF 128
#define DE 64
#define D  128
#define K1 192   // gemm1 LHS row: [e(64), fbar(128)]
#define K0 192   // gemm0 LHS row: [f(128), ebar(64)]
#define K2 256   // gemm2 LHS row: [h0(128), mh1(128)]

typedef __attribute__((ext_vector_type(8))) short bf16x8;
typedef __attribute__((ext_vector_type(4))) float f32x4;

__device__ __forceinline__ unsigned short f2bf(float x) {
  union { float f; unsigned int u; } v; v.f = x;
  unsigned int r = (v.u + 0x7FFFu + ((v.u >> 16) & 1u)) >> 16;
  return (unsigned short)r;
}

__device__ __forceinline__ float bf2f(unsigned short s) {
  union { float f; unsigned int u; } v; v.u = ((unsigned int)s) << 16;
  return v.f;
}

// packed f32x2 -> bf16x2 (compiler emits v_cvt_pk_bf16_f32)
__device__ __forceinline__ unsigned int pk2(float lo, float hi) {
  __hip_bfloat162 h = __float22bfloat162_rn(float2{lo, hi});
  union { __hip_bfloat162 h; unsigned int u; } c; c.h = h;
  return c.u;
}

__device__ __forceinline__ bf16x8 pack8(float4 a, float4 b) {
  union { bf16x8 v; unsigned int u[4]; } c;
  c.u[0] = pk2(a.x, a.y); c.u[1] = pk2(a.z, a.w);
  c.u[2] = pk2(b.x, b.y); c.u[3] = pk2(b.z, b.w);
  return c.v;
}

// average two bf16x8 vectors (f32 math, repack)
__device__ __forceinline__ bf16x8 avg8(bf16x8 A, bf16x8 Bv) {
  union { bf16x8 v; unsigned short s[8]; } ua, ub;
  union { bf16x8 v; unsigned int u[4]; } uo;
  ua.v = A; ub.v = Bv;
#pragma unroll
  for (int p = 0; p < 4; p++) {
    float x0 = 0.5f * (bf2f(ua.s[2 * p]) + bf2f(ub.s[2 * p]));
    float x1 = 0.5f * (bf2f(ua.s[2 * p + 1]) + bf2f(ub.s[2 * p + 1]));
    uo.u[p] = pk2(x0, x1);
  }
  return uo.v;
}

// ---------- prep: fused weight-fusion + feats f32->bf16 ----------
// blocks [0,192):   weight GEMM rows (two 128-thread halves per block)
// blocks [192,256): W2F copy
// blocks [256,2304): cvt feats streaming
__global__ __launch_bounds__(256) void prep(
    const float* __restrict__ prep_W, const float* __restrict__ edge_prep_W,
    const float* __restrict__ Wn_self, const float* __restrict__ Wn_neigh,
    const float* __restrict__ We_self, const float* __restrict__ We_neigh,
    const float* __restrict__ feats,
    unsigned short* __restrict__ W0F, unsigned short* __restrict__ W1F,
    unsigned short* __restrict__ W2F, unsigned short* __restrict__ fb) {
  int bx = blockIdx.x;
  if (bx < 192) {
    int half = threadIdx.x >> 7, n = threadIdx.x & 127;
    int wg = bx * 2 + half;       // [0,384)
    int mp = wg / 192, k = wg % 192;
    const float* eprow = edge_prep_W + (size_t)mp * 64 * 128;
    const float* A0 = (k < 128) ? prep_W + (size_t)k * 128 : eprow + (size_t)(k - 128) * 128;
    const float* B0 = ((k < 128) ? Wn_self : Wn_neigh) + (size_t)(mp * 2) * 128 * 128;
    const float* A1 = (k < 64)  ? eprow + (size_t)k * 128 : prep_W + (size_t)(k - 64) * 128;
    const float* B1 = ((k < 64)  ? We_self : We_neigh) + (size_t)(mp * 2) * 128 * 128;
    __shared__ float sA0[2][128], sA1[2][128];
    sA0[half][n] = A0[n]; sA1[half][n] = A1[n];
    __syncthreads();
    float acc0 = 0.f, acc1 = 0.f;
#pragma unroll 8
    for (int j = 0; j < 128; j++) {
      acc0 += sA0[half][j] * B0[j * 128 + n];
      acc1 += sA1[half][j] * B1[j * 128 + n];
    }
    int ks = k >> 5, l4 = (k >> 3) & 3, e = k & 7;
    W0F[(((size_t)(mp * 6 + ks) * 4 + l4) * 128 + n) * 8 + e] = f2bf(acc0);
    W1F[(((size_t)(mp * 6 + ks) * 4 + l4) * 128 + n) * 8 + e] = f2bf(acc1);
  } else if (bx < 256) {
    int half = threadIdx.x >> 7, n = threadIdx.x & 127;
    int w2 = (bx - 192) * 2 + half;   // [0,128)
    int mp = w2 >> 6;
    int kb = (w2 & 63) * 4;
#pragma unroll
    for (int kk = 0; kk < 4; kk++) {
      int k = kb + kk;
      float v = (k < 128) ? Wn_self[(((size_t)(mp * 2) + 1) * 128 + k) * 128 + n]
                          : Wn_neigh[(((size_t)(mp * 2) + 1) * 128 + (k - 128)) * 128 + n];
      int ks = k >> 5, l4 = (k >> 3) & 3, e = k & 7;
      W2F[(((size_t)(mp * 8 + ks) * 4 + l4) * 128 + n) * 8 + e] = f2bf(v);
    }
  } else {
    const int n = NN * DF / 8;
    for (int i = (bx - 256) * 256 + threadIdx.x; i < n; i += 2048 * 256) {
      const float4* s = (const float4*)(feats + (size_t)i * 8);
      float4 v0 = s[0], v1 = s[1];
      *(bf16x8*)(fb + (size_t)i * 8) = pack8(v0, v1);
    }
  }
}

// ---------- C: gathered GEMM1 + relu + pool, fused ebar + feats copy ----------
// One seed per wave, 4 seeds/block (256 thr, 4-wave barrier groups).
// W staged in TWO 64-col halves through one 24.6KB LDS buffer.
// Caps: VGPR(<=128) -> 4 waves/SIMD = 16 waves/CU; LDS allows 6 blocks/CU.
__global__ __launch_bounds__(256, 4) void gemm1_pool(
    const int* __restrict__ ids,
    const int* __restrict__ n2e0, const int* __restrict__ n2e1,
    const int* __restrict__ adj0, const int* __restrict__ adj1,
    const float* __restrict__ ee0, const float* __restrict__ ee1,
    const unsigned short* __restrict__ featsbf,
    const unsigned short* __restrict__ W1F,
    unsigned short* __restrict__ G0, unsigned short* __restrict__ G2) {
  __shared__ unsigned short sW[6 * 4 * 64 * 8];   // 24576 B: one 64-col half of W
  int wg   = blockIdx.x;     // 2 * 1024
  int mp   = wg >> 10;
  int tile = wg & 1023;
  int wave = threadIdx.x >> 6, lane = threadIdx.x & 63;
  int l15 = lane & 15, l4 = lane >> 4;
  int seed = tile * 4 + wave;

  const int*   n2e = mp ? n2e1 : n2e0;
  const int*   adj = mp ? adj1 : adj0;
  const float* ee  = mp ? ee1 : ee0;
  const uint4* Wsrc = (const uint4*)(W1F + (size_t)mp * 24576);   // [ksl4(24)][col(128)] x 16B

  // index chain first (longest dependent path)
  int id = ids[seed];   // wave-uniform
  int eidA = n2e[(size_t)id * S + l15];
  int eidB = n2e[(size_t)id * S + 16 + l15];
  int2 abA = *(const int2*)(adj + (size_t)eidA * 2);
  int2 abB = *(const int2*)(adj + (size_t)eidB * 2);

  int eids[2] = {eidA, eidB};
  int2 abx[2] = {abA, abB};

  bf16x8 a[2][6];          // A fragments: [mi][ks]
  float esum[2][8];        // f32 partial sums of raw ee (for ebar)
#pragma unroll
  for (int j = 0; j < 8; j++) { esum[0][j] = 0.f; esum[1][j] = 0.f; }

#pragma unroll
  for (int mi = 0; mi < 2; mi++) {
    const float* ep = ee + (size_t)eids[mi] * DE + l4 * 8;
#pragma unroll
    for (int ks = 0; ks < 2; ks++) {
      float4 v0 = *(const float4*)(ep + ks * 32);
      float4 v1 = *(const float4*)(ep + ks * 32 + 4);
      esum[ks][0] += v0.x; esum[ks][1] += v0.y; esum[ks][2] += v0.z; esum[ks][3] += v0.w;
      esum[ks][4] += v1.x; esum[ks][5] += v1.y; esum[ks][6] += v1.z; esum[ks][7] += v1.w;
      a[mi][ks] = pack8(v0, v1);
    }
    const unsigned short* fa = featsbf + (size_t)abx[mi].x * DF + l4 * 8;
    const unsigned short* fb = featsbf + (size_t)abx[mi].y * DF + l4 * 8;
#pragma unroll
    for (int ks = 2; ks < 6; ks++) {
      int off = (ks - 2) * 32;
      bf16x8 va = *(const bf16x8*)(fa + off);
      bf16x8 vb = *(const bf16x8*)(fb + off);
      a[mi][ks] = avg8(va, vb);
    }
  }

  // MFMA: M=32 (2 mi), K=192 (6 ks); N=128 as two 64-col halves, W half-staged
  unsigned short* G2row = G2 + ((size_t)(mp * B + seed)) * K2 + 128;
#pragma unroll 1
  for (int half = 0; half < 2; half++) {
    if (half) __syncthreads();   // protect sW reads of previous half
    for (int u = threadIdx.x; u < 1536; u += 256) {
      int ksl4 = u >> 6, c = u & 63;
      ((uint4*)sW)[u] = Wsrc[ksl4 * 128 + half * 64 + c];
    }
    __syncthreads();             // sW half visible

    f32x4 acc[2][4] = {};
#pragma unroll
    for (int ks = 0; ks < 6; ks++) {
      bf16x8 bw[4];
#pragma unroll
      for (int ni = 0; ni < 4; ni++) {
        int c = ni * 16 + l15;
        bw[ni] = *(const bf16x8*)(sW + ((size_t)((ks * 4 + l4) * 64 + c)) * 8);
      }
#pragma unroll
      for (int mi = 0; mi < 2; mi++)
#pragma unroll
        for (int ni = 0; ni < 4; ni++)
          acc[mi][ni] = __builtin_amdgcn_mfma_f32_16x16x32_bf16(a[mi][ks], bw[ni], acc[mi][ni], 0, 0, 0);
    }
    // relu + mean over 32 edge rows
#pragma unroll
    for (int ni = 0; ni < 4; ni++) {
      float ssum = 0.f;
#pragma unroll
      for (int mi = 0; mi < 2; mi++)
#pragma unroll
        for (int q = 0; q < 4; q++)
          ssum += fmaxf(acc[mi][ni][q], 0.f);
      ssum += __shfl_xor(ssum, 16);
      ssum += __shfl_xor(ssum, 32);
      if (l4 == 0) G2row[half * 64 + ni * 16 + l15] = f2bf(ssum * (1.f / 32.f));
    }
  }

  // ebar: butterfly over the 16 l15 lanes
#pragma unroll
  for (int ks = 0; ks < 2; ks++)
#pragma unroll
    for (int j = 0; j < 8; j++) {
      float v = esum[ks][j];
      v += __shfl_xor(v, 1); v += __shfl_xor(v, 2);
      v += __shfl_xor(v, 4); v += __shfl_xor(v, 8);
      esum[ks][j] = v;
    }
  unsigned short* G0row = G0 + ((size_t)(mp * B + seed)) * K0;
  if (l15 == 0) {
#pragma unroll
    for (int ks = 0; ks < 2; ks++) {
      float4 lo, hi;
      lo.x = esum[ks][0] * (1.f / 32.f); lo.y = esum[ks][1] * (1.f / 32.f);
      lo.z = esum[ks][2] * (1.f / 32.f); lo.w = esum[ks][3] * (1.f / 32.f);
      hi.x = esum[ks][4] * (1.f / 32.f); hi.y = esum[ks][5] * (1.f / 32.f);
      hi.z = esum[ks][6] * (1.f / 32.f); hi.w = esum[ks][7] * (1.f / 32.f);
      *(bf16x8*)(G0row + 128 + ks * 32 + l4 * 8) = pack8(lo, hi);
    }
  }
  // feats copy: G0[seed][0:128] = featsbf[id] (one coalesced 256B store/wave)
  ((unsigned int*)G0row)[lane] = ((const unsigned int*)(featsbf + (size_t)id * DF))[lane];
}

// ---------- D/F: dense GEMM (4096 x K @ K x 128), relu, write out ----------
template <int K>
__global__ __launch_bounds__(256) void gemm_dense(
    const unsigned short* __restrict__ G,    // [2][4096][K] bf16
    const unsigned short* __restrict__ WF,   // fragment layout [mp][K/32][4][128][8]
    float* __restrict__ outA,                // stride 256 rows (pre-offset for cols)
    unsigned short* __restrict__ outB16) {   // optional bf16 copy (G2 cols 0:128), or null
  const int KP = K + 8;
  const int KS = K / 32;
  __shared__ unsigned short Gt[32 * KP];
  int wg   = blockIdx.x;       // 2 * 128
  int mp   = wg >> 7;
  int tile = wg & 127;
  const unsigned short* Gsrc = G + ((size_t)mp * B + tile * 32) * K;
  const unsigned short* Wf = WF + (size_t)mp * KS * 4 * 128 * 8;
  int t = threadIdx.x;

  const int NU = 32 * K / 8;   // uint4 chunks
  for (int u = t; u < NU; u += 256) {
    int row = u / (K / 8), col = u % (K / 8);
    *(uint4*)(&Gt[row * KP + col * 8]) = *(const uint4*)(Gsrc + (size_t)row * K + col * 8);
  }
  __syncthreads();

  int wave = t >> 6, lane = t & 63;
  int l15 = lane & 15, l4 = lane >> 4;
  f32x4 acc[2][2] = {};
#pragma unroll
  for (int ks = 0; ks < KS; ks++) {
    bf16x8 af[2], bw[2];
#pragma unroll
    for (int mi = 0; mi < 2; mi++)
      af[mi] = *(const bf16x8*)(&Gt[(mi * 16 + l15) * KP + ks * 32 + l4 * 8]);
#pragma unroll
    for (int ni = 0; ni < 2; ni++) {
      int c = wave * 32 + ni * 16 + l15;
      bw[ni] = *(const bf16x8*)(Wf + ((size_t)((ks * 4 + l4) * 128 + c)) * 8);
    }
#pragma unroll
    for (int mi = 0; mi < 2; mi++)
#pragma unroll
      for (int ni = 0; ni < 2; ni++)
        acc[mi][ni] = __builtin_amdgcn_mfma_f32_16x16x32_bf16(af[mi], bw[ni], acc[mi][ni], 0, 0, 0);
  }

#pragma unroll
  for (int mi = 0; mi < 2; mi++)
#pragma unroll
    for (int ni = 0; ni < 2; ni++)
#pragma unroll
      for (int q = 0; q < 4; q++) {
        int row = mi * 16 + l4 * 4 + q;
        int col = wave * 32 + ni * 16 + l15;
        float v = fmaxf(acc[mi][ni][q], 0.f);
        size_t r = (size_t)(mp * B) + tile * 32 + row;
        outA[r * 256 + col] = v;
        if (outB16) outB16[r * 256 + col] = f2bf(v);
      }
}

extern "C" void kernel_launch(void* const* d_in, const int* in_sizes, int n_in,
                              void* d_out, int out_size, void* d_ws, size_t ws_size,
                              hipStream_t stream) {
  (void)in_sizes; (void)n_in; (void)out_size; (void)ws_size;
  const int*   ids    = (const int*)d_in[0];
  const float* feats  = (const float*)d_in[1];
  const int*   n2e0   = (const int*)d_in[2];
  const int*   n2e1   = (const int*)d_in[3];
  const int*   adj0   = (const int*)d_in[4];
  const int*   adj1   = (const int*)d_in[5];
  const float* ee0    = (const float*)d_in[6];
  const float* ee1    = (const float*)d_in[7];
  const float* prep_W = (const float*)d_in[8];
  const float* eprep  = (const float*)d_in[9];
  const float* WnS    = (const float*)d_in[10];
  const float* WnN    = (const float*)d_in[11];
  const float* WeS    = (const float*)d_in[12];
  const float* WeN    = (const float*)d_in[13];
  float* out = (float*)d_out;

  char* ws = (char*)d_ws;
  unsigned short* featsbf = (unsigned short*)(ws);                  // 25,600,000 B
  unsigned short* W0F = (unsigned short*)(ws + 25600000);           // 98304 B
  unsigned short* W1F = (unsigned short*)(ws + 25698304);           // 98304 B
  unsigned short* W2F = (unsigned short*)(ws + 25796608);           // 131072 B
  unsigned short* G0  = (unsigned short*)(ws + 25927680);           // 3,145,728 B
  unsigned short* G2  = (unsigned short*)(ws + 29073408);           // 4,194,304 B

  hipLaunchKernelGGL(prep, dim3(2304), dim3(256), 0, stream,
                     prep_W, eprep, WnS, WnN, WeS, WeN, feats, W0F, W1F, W2F, featsbf);
  hipLaunchKernelGGL(gemm1_pool, dim3(2 * 1024), dim3(256), 0, stream,
                     ids, n2e0, n2e1, adj0, adj1, ee0, ee1, featsbf, W1F, G0, G2);
  hipLaunchKernelGGL((gemm_dense<192>), dim3(2 * 128), dim3(256), 0, stream,
                     G0, W0F, out, G2);
  hipLaunchKernelGGL((gemm_dense<256>), dim3(2 * 128), dim3(256), 0, stream,
                     G2, W2F, out + 128, (unsigned short*)nullptr);
}

// Round 8
// 88.212 us; speedup vs baseline: 1.0973x; 1.0973x over previous
//
#include <hip/hip_runtime.h>
#include <hip/hip_bf16.h>

#define NN 100000
#define NE 400000
#define S  32
#define B  4096
#define DF 128
#define DE 64
#define D  128
#define K1 192   // gemm1 LHS row: [e(64), fbar(128)]
#define K0 192   // gemm0 LHS row: [f(128), ebar(64)]
#define K2 256   // gemm2 LHS row: [h0(128), mh1(128)]

typedef __attribute__((ext_vector_type(8))) short bf16x8;
typedef __attribute__((ext_vector_type(4))) float f32x4;

__device__ __forceinline__ unsigned short f2bf(float x) {
  union { float f; unsigned int u; } v; v.f = x;
  unsigned int r = (v.u + 0x7FFFu + ((v.u >> 16) & 1u)) >> 16;
  return (unsigned short)r;
}

__device__ __forceinline__ float bf2f(unsigned short s) {
  union { float f; unsigned int u; } v; v.u = ((unsigned int)s) << 16;
  return v.f;
}

// packed f32x2 -> bf16x2 (compiler emits v_cvt_pk_bf16_f32)
__device__ __forceinline__ unsigned int pk2(float lo, float hi) {
  __hip_bfloat162 h = __float22bfloat162_rn(float2{lo, hi});
  union { __hip_bfloat162 h; unsigned int u; } c; c.h = h;
  return c.u;
}

__device__ __forceinline__ bf16x8 pack8(float4 a, float4 b) {
  union { bf16x8 v; unsigned int u[4]; } c;
  c.u[0] = pk2(a.x, a.y); c.u[1] = pk2(a.z, a.w);
  c.u[2] = pk2(b.x, b.y); c.u[3] = pk2(b.z, b.w);
  return c.v;
}

// average two bf16x8 vectors (f32 math, repack)
__device__ __forceinline__ bf16x8 avg8(bf16x8 A, bf16x8 Bv) {
  union { bf16x8 v; unsigned short s[8]; } ua, ub;
  union { bf16x8 v; unsigned int u[4]; } uo;
  ua.v = A; ub.v = Bv;
#pragma unroll
  for (int p = 0; p < 4; p++) {
    float x0 = 0.5f * (bf2f(ua.s[2 * p]) + bf2f(ub.s[2 * p]));
    float x1 = 0.5f * (bf2f(ua.s[2 * p + 1]) + bf2f(ub.s[2 * p + 1]));
    uo.u[p] = pk2(x0, x1);
  }
  return uo.v;
}

// ---------- prep: fused weight-fusion + feats f32->bf16 ----------
// blocks [0,192):   weight GEMM rows (two 128-thread halves per block)
// blocks [192,256): W2F copy
// blocks [256,2304): cvt feats streaming
__global__ __launch_bounds__(256) void prep(
    const float* __restrict__ prep_W, const float* __restrict__ edge_prep_W,
    const float* __restrict__ Wn_self, const float* __restrict__ Wn_neigh,
    const float* __restrict__ We_self, const float* __restrict__ We_neigh,
    const float* __restrict__ feats,
    unsigned short* __restrict__ W0F, unsigned short* __restrict__ W1F,
    unsigned short* __restrict__ W2F, unsigned short* __restrict__ fb) {
  int bx = blockIdx.x;
  if (bx < 192) {
    int half = threadIdx.x >> 7, n = threadIdx.x & 127;
    int wg = bx * 2 + half;       // [0,384)
    int mp = wg / 192, k = wg % 192;
    const float* eprow = edge_prep_W + (size_t)mp * 64 * 128;
    const float* A0 = (k < 128) ? prep_W + (size_t)k * 128 : eprow + (size_t)(k - 128) * 128;
    const float* B0 = ((k < 128) ? Wn_self : Wn_neigh) + (size_t)(mp * 2) * 128 * 128;
    const float* A1 = (k < 64)  ? eprow + (size_t)k * 128 : prep_W + (size_t)(k - 64) * 128;
    const float* B1 = ((k < 64)  ? We_self : We_neigh) + (size_t)(mp * 2) * 128 * 128;
    __shared__ float sA0[2][128], sA1[2][128];
    sA0[half][n] = A0[n]; sA1[half][n] = A1[n];
    __syncthreads();
    float acc0 = 0.f, acc1 = 0.f;
#pragma unroll 8
    for (int j = 0; j < 128; j++) {
      acc0 += sA0[half][j] * B0[j * 128 + n];
      acc1 += sA1[half][j] * B1[j * 128 + n];
    }
    int ks = k >> 5, l4 = (k >> 3) & 3, e = k & 7;
    W0F[(((size_t)(mp * 6 + ks) * 4 + l4) * 128 + n) * 8 + e] = f2bf(acc0);
    W1F[(((size_t)(mp * 6 + ks) * 4 + l4) * 128 + n) * 8 + e] = f2bf(acc1);
  } else if (bx < 256) {
    int half = threadIdx.x >> 7, n = threadIdx.x & 127;
    int w2 = (bx - 192) * 2 + half;   // [0,128)
    int mp = w2 >> 6;
    int kb = (w2 & 63) * 4;
#pragma unroll
    for (int kk = 0; kk < 4; kk++) {
      int k = kb + kk;
      float v = (k < 128) ? Wn_self[(((size_t)(mp * 2) + 1) * 128 + k) * 128 + n]
                          : Wn_neigh[(((size_t)(mp * 2) + 1) * 128 + (k - 128)) * 128 + n];
      int ks = k >> 5, l4 = (k >> 3) & 3, e = k & 7;
      W2F[(((size_t)(mp * 8 + ks) * 4 + l4) * 128 + n) * 8 + e] = f2bf(v);
    }
  } else {
    const int n = NN * DF / 8;
    for (int i = (bx - 256) * 256 + threadIdx.x; i < n; i += 2048 * 256) {
      const float4* s = (const float4*)(feats + (size_t)i * 8);
      float4 v0 = s[0], v1 = s[1];
      *(bf16x8*)(fb + (size_t)i * 8) = pack8(v0, v1);
    }
  }
}

// ---------- C: gathered GEMM1 + relu + pool, fused ebar + feats copy ----------
// One seed per wave, 4 seeds/block. W staged in TWO 64-col halves through one
// 24.6KB LDS buffer (6 blocks/CU by LDS). NO launch_bounds occupancy directive:
// every attempt to force occupancy (r5 (512,6)->VGPR40, r7 (256,4)->VGPR64)
// made the compiler clamp VGPRs and spill (WRITE_SIZE 185/66 MB). Unconstrained
// builds land at VGPR~80-84 (r3/r4) -> 6 waves/SIMD -> 24 waves/CU here.
__global__ __launch_bounds__(256) void gemm1_pool(
    const int* __restrict__ ids,
    const int* __restrict__ n2e0, const int* __restrict__ n2e1,
    const int* __restrict__ adj0, const int* __restrict__ adj1,
    const float* __restrict__ ee0, const float* __restrict__ ee1,
    const unsigned short* __restrict__ featsbf,
    const unsigned short* __restrict__ W1F,
    unsigned short* __restrict__ G0, unsigned short* __restrict__ G2) {
  __shared__ unsigned short sW[6 * 4 * 64 * 8];   // 24576 B: one 64-col half of W
  int wg   = blockIdx.x;     // 2 * 1024
  int mp   = wg >> 10;
  int tile = wg & 1023;
  int wave = threadIdx.x >> 6, lane = threadIdx.x & 63;
  int l15 = lane & 15, l4 = lane >> 4;
  int seed = tile * 4 + wave;

  const int*   n2e = mp ? n2e1 : n2e0;
  const int*   adj = mp ? adj1 : adj0;
  const float* ee  = mp ? ee1 : ee0;
  const uint4* Wsrc = (const uint4*)(W1F + (size_t)mp * 24576);   // [ksl4(24)][col(128)] x 16B

  // index chain first (longest dependent path)
  int id = ids[seed];   // wave-uniform
  int eidA = n2e[(size_t)id * S + l15];
  int eidB = n2e[(size_t)id * S + 16 + l15];
  int2 abA = *(const int2*)(adj + (size_t)eidA * 2);
  int2 abB = *(const int2*)(adj + (size_t)eidB * 2);

  int eids[2] = {eidA, eidB};
  int2 abx[2] = {abA, abB};

  bf16x8 a[2][6];          // A fragments: [mi][ks]
  float esum[2][8];        // f32 partial sums of raw ee (for ebar)
#pragma unroll
  for (int j = 0; j < 8; j++) { esum[0][j] = 0.f; esum[1][j] = 0.f; }

#pragma unroll
  for (int mi = 0; mi < 2; mi++) {
    const float* ep = ee + (size_t)eids[mi] * DE + l4 * 8;
#pragma unroll
    for (int ks = 0; ks < 2; ks++) {
      float4 v0 = *(const float4*)(ep + ks * 32);
      float4 v1 = *(const float4*)(ep + ks * 32 + 4);
      esum[ks][0] += v0.x; esum[ks][1] += v0.y; esum[ks][2] += v0.z; esum[ks][3] += v0.w;
      esum[ks][4] += v1.x; esum[ks][5] += v1.y; esum[ks][6] += v1.z; esum[ks][7] += v1.w;
      a[mi][ks] = pack8(v0, v1);
    }
    const unsigned short* fa = featsbf + (size_t)abx[mi].x * DF + l4 * 8;
    const unsigned short* fb = featsbf + (size_t)abx[mi].y * DF + l4 * 8;
#pragma unroll
    for (int ks = 2; ks < 6; ks++) {
      int off = (ks - 2) * 32;
      bf16x8 va = *(const bf16x8*)(fa + off);
      bf16x8 vb = *(const bf16x8*)(fb + off);
      a[mi][ks] = avg8(va, vb);
    }
  }

  // MFMA: M=32 (2 mi), K=192 (6 ks); N=128 as two 64-col halves, W half-staged
  unsigned short* G2row = G2 + ((size_t)(mp * B + seed)) * K2 + 128;
#pragma unroll 1
  for (int half = 0; half < 2; half++) {
    if (half) __syncthreads();   // protect sW reads of previous half
    for (int u = threadIdx.x; u < 1536; u += 256) {
      int ksl4 = u >> 6, c = u & 63;
      ((uint4*)sW)[u] = Wsrc[ksl4 * 128 + half * 64 + c];
    }
    __syncthreads();             // sW half visible

    f32x4 acc[2][4] = {};
#pragma unroll
    for (int ks = 0; ks < 6; ks++) {
      bf16x8 bw[4];
#pragma unroll
      for (int ni = 0; ni < 4; ni++) {
        int c = ni * 16 + l15;
        bw[ni] = *(const bf16x8*)(sW + ((size_t)((ks * 4 + l4) * 64 + c)) * 8);
      }
#pragma unroll
      for (int mi = 0; mi < 2; mi++)
#pragma unroll
        for (int ni = 0; ni < 4; ni++)
          acc[mi][ni] = __builtin_amdgcn_mfma_f32_16x16x32_bf16(a[mi][ks], bw[ni], acc[mi][ni], 0, 0, 0);
    }
    // relu + mean over 32 edge rows
#pragma unroll
    for (int ni = 0; ni < 4; ni++) {
      float ssum = 0.f;
#pragma unroll
      for (int mi = 0; mi < 2; mi++)
#pragma unroll
        for (int q = 0; q < 4; q++)
          ssum += fmaxf(acc[mi][ni][q], 0.f);
      ssum += __shfl_xor(ssum, 16);
      ssum += __shfl_xor(ssum, 32);
      if (l4 == 0) G2row[half * 64 + ni * 16 + l15] = f2bf(ssum * (1.f / 32.f));
    }
  }

  // ebar: butterfly over the 16 l15 lanes
#pragma unroll
  for (int ks = 0; ks < 2; ks++)
#pragma unroll
    for (int j = 0; j < 8; j++) {
      float v = esum[ks][j];
      v += __shfl_xor(v, 1); v += __shfl_xor(v, 2);
      v += __shfl_xor(v, 4); v += __shfl_xor(v, 8);
      esum[ks][j] = v;
    }
  unsigned short* G0row = G0 + ((size_t)(mp * B + seed)) * K0;
  if (l15 == 0) {
#pragma unroll
    for (int ks = 0; ks < 2; ks++) {
      float4 lo, hi;
      lo.x = esum[ks][0] * (1.f / 32.f); lo.y = esum[ks][1] * (1.f / 32.f);
      lo.z = esum[ks][2] * (1.f / 32.f); lo.w = esum[ks][3] * (1.f / 32.f);
      hi.x = esum[ks][4] * (1.f / 32.f); hi.y = esum[ks][5] * (1.f / 32.f);
      hi.z = esum[ks][6] * (1.f / 32.f); hi.w = esum[ks][7] * (1.f / 32.f);
      *(bf16x8*)(G0row + 128 + ks * 32 + l4 * 8) = pack8(lo, hi);
    }
  }
  // feats copy: G0[seed][0:128] = featsbf[id] (one coalesced 256B store/wave)
  ((unsigned int*)G0row)[lane] = ((const unsigned int*)(featsbf + (size_t)id * DF))[lane];
}

// ---------- D/F: dense GEMM (4096 x K @ K x 128), relu, write out ----------
template <int K>
__global__ __launch_bounds__(256) void gemm_dense(
    const unsigned short* __restrict__ G,    // [2][4096][K] bf16
    const unsigned short* __restrict__ WF,   // fragment layout [mp][K/32][4][128][8]
    float* __restrict__ outA,                // stride 256 rows (pre-offset for cols)
    unsigned short* __restrict__ outB16) {   // optional bf16 copy (G2 cols 0:128), or null
  const int KP = K + 8;
  const int KS = K / 32;
  __shared__ unsigned short Gt[32 * KP];
  int wg   = blockIdx.x;       // 2 * 128
  int mp   = wg >> 7;
  int tile = wg & 127;
  const unsigned short* Gsrc = G + ((size_t)mp * B + tile * 32) * K;
  const unsigned short* Wf = WF + (size_t)mp * KS * 4 * 128 * 8;
  int t = threadIdx.x;

  const int NU = 32 * K / 8;   // uint4 chunks
  for (int u = t; u < NU; u += 256) {
    int row = u / (K / 8), col = u % (K / 8);
    *(uint4*)(&Gt[row * KP + col * 8]) = *(const uint4*)(Gsrc + (size_t)row * K + col * 8);
  }
  __syncthreads();

  int wave = t >> 6, lane = t & 63;
  int l15 = lane & 15, l4 = lane >> 4;
  f32x4 acc[2][2] = {};
#pragma unroll
  for (int ks = 0; ks < KS; ks++) {
    bf16x8 af[2], bw[2];
#pragma unroll
    for (int mi = 0; mi < 2; mi++)
      af[mi] = *(const bf16x8*)(&Gt[(mi * 16 + l15) * KP + ks * 32 + l4 * 8]);
#pragma unroll
    for (int ni = 0; ni < 2; ni++) {
      int c = wave * 32 + ni * 16 + l15;
      bw[ni] = *(const bf16x8*)(Wf + ((size_t)((ks * 4 + l4) * 128 + c)) * 8);
    }
#pragma unroll
    for (int mi = 0; mi < 2; mi++)
#pragma unroll
      for (int ni = 0; ni < 2; ni++)
        acc[mi][ni] = __builtin_amdgcn_mfma_f32_16x16x32_bf16(af[mi], bw[ni], acc[mi][ni], 0, 0, 0);
  }

#pragma unroll
  for (int mi = 0; mi < 2; mi++)
#pragma unroll
    for (int ni = 0; ni < 2; ni++)
#pragma unroll
      for (int q = 0; q < 4; q++) {
        int row = mi * 16 + l4 * 4 + q;
        int col = wave * 32 + ni * 16 + l15;
        float v = fmaxf(acc[mi][ni][q], 0.f);
        size_t r = (size_t)(mp * B) + tile * 32 + row;
        outA[r * 256 + col] = v;
        if (outB16) outB16[r * 256 + col] = f2bf(v);
      }
}

extern "C" void kernel_launch(void* const* d_in, const int* in_sizes, int n_in,
                              void* d_out, int out_size, void* d_ws, size_t ws_size,
                              hipStream_t stream) {
  (void)in_sizes; (void)n_in; (void)out_size; (void)ws_size;
  const int*   ids    = (const int*)d_in[0];
  const float* feats  = (const float*)d_in[1];
  const int*   n2e0   = (const int*)d_in[2];
  const int*   n2e1   = (const int*)d_in[3];
  const int*   adj0   = (const int*)d_in[4];
  const int*   adj1   = (const int*)d_in[5];
  const float* ee0    = (const float*)d_in[6];
  const float* ee1    = (const float*)d_in[7];
  const float* prep_W = (const float*)d_in[8];
  const float* eprep  = (const float*)d_in[9];
  const float* WnS    = (const float*)d_in[10];
  const float* WnN    = (const float*)d_in[11];
  const float* WeS    = (const float*)d_in[12];
  const float* WeN    = (const float*)d_in[13];
  float* out = (float*)d_out;

  char* ws = (char*)d_ws;
  unsigned short* featsbf = (unsigned short*)(ws);                  // 25,600,000 B
  unsigned short* W0F = (unsigned short*)(ws + 25600000);           // 98304 B
  unsigned short* W1F = (unsigned short*)(ws + 25698304);           // 98304 B
  unsigned short* W2F = (unsigned short*)(ws + 25796608);           // 131072 B
  unsigned short* G0  = (unsigned short*)(ws + 25927680);           // 3,145,728 B
  unsigned short* G2  = (unsigned short*)(ws + 29073408);           // 4,194,304 B

  hipLaunchKernelGGL(prep, dim3(2304), dim3(256), 0, stream,
                     prep_W, eprep, WnS, WnN, WeS, WeN, feats, W0F, W1F, W2F, featsbf);
  hipLaunchKernelGGL(gemm1_pool, dim3(2 * 1024), dim3(256), 0, stream,
                     ids, n2e0, n2e1, adj0, adj1, ee0, ee1, featsbf, W1F, G0, G2);
  hipLaunchKernelGGL((gemm_dense<192>), dim3(2 * 128), dim3(256), 0, stream,
                     G0, W0F, out, G2);
  hipLaunchKernelGGL((gemm_dense<256>), dim3(2 * 128), dim3(256), 0, stream,
                     G2, W2F, out + 128, (unsigned short*)nullptr);
}

// Round 9
// 74.497 us; speedup vs baseline: 1.2993x; 1.1841x over previous
//
#include <hip/hip_runtime.h>
#include <hip/hip_bf16.h>

#define NN 100000
#define NE 400000
#define S  32
#define B  4096
#define DF 128
#define DE 64
#define D  128
#define K1 192   // gemm1 LHS row: [e(64), fbar(128)]
#define K0 192   // gemm0 LHS row: [f(128), ebar(64)]
#define K2 256   // gemm2 LHS row: [h0(128), mh1(128)]

typedef __attribute__((ext_vector_type(8))) short bf16x8;
typedef __attribute__((ext_vector_type(4))) float f32x4;

__device__ __forceinline__ unsigned short f2bf(float x) {
  union { float f; unsigned int u; } v; v.f = x;
  unsigned int r = (v.u + 0x7FFFu + ((v.u >> 16) & 1u)) >> 16;
  return (unsigned short)r;
}

__device__ __forceinline__ float bf2f(unsigned short s) {
  union { float f; unsigned int u; } v; v.u = ((unsigned int)s) << 16;
  return v.f;
}

// packed f32x2 -> bf16x2 (compiler emits v_cvt_pk_bf16_f32)
__device__ __forceinline__ unsigned int pk2(float lo, float hi) {
  __hip_bfloat162 h = __float22bfloat162_rn(float2{lo, hi});
  union { __hip_bfloat162 h; unsigned int u; } c; c.h = h;
  return c.u;
}

__device__ __forceinline__ bf16x8 pack8(float4 a, float4 b) {
  union { bf16x8 v; unsigned int u[4]; } c;
  c.u[0] = pk2(a.x, a.y); c.u[1] = pk2(a.z, a.w);
  c.u[2] = pk2(b.x, b.y); c.u[3] = pk2(b.z, b.w);
  return c.v;
}

// average two bf16x8 vectors (f32 math, repack)
__device__ __forceinline__ bf16x8 avg8(bf16x8 A, bf16x8 Bv) {
  union { bf16x8 v; unsigned short s[8]; } ua, ub;
  union { bf16x8 v; unsigned int u[4]; } uo;
  ua.v = A; ub.v = Bv;
#pragma unroll
  for (int p = 0; p < 4; p++) {
    float x0 = 0.5f * (bf2f(ua.s[2 * p]) + bf2f(ub.s[2 * p]));
    float x1 = 0.5f * (bf2f(ua.s[2 * p + 1]) + bf2f(ub.s[2 * p + 1]));
    uo.u[p] = pk2(x0, x1);
  }
  return uo.v;
}

// ---------- prep: fused weight-fusion + feats f32->bf16 ----------
__global__ __launch_bounds__(256) void prep(
    const float* __restrict__ prep_W, const float* __restrict__ edge_prep_W,
    const float* __restrict__ Wn_self, const float* __restrict__ Wn_neigh,
    const float* __restrict__ We_self, const float* __restrict__ We_neigh,
    const float* __restrict__ feats,
    unsigned short* __restrict__ W0F, unsigned short* __restrict__ W1F,
    unsigned short* __restrict__ W2F, unsigned short* __restrict__ fb) {
  int bx = blockIdx.x;
  if (bx < 192) {
    int half = threadIdx.x >> 7, n = threadIdx.x & 127;
    int wg = bx * 2 + half;       // [0,384)
    int mp = wg / 192, k = wg % 192;
    const float* eprow = edge_prep_W + (size_t)mp * 64 * 128;
    const float* A0 = (k < 128) ? prep_W + (size_t)k * 128 : eprow + (size_t)(k - 128) * 128;
    const float* B0 = ((k < 128) ? Wn_self : Wn_neigh) + (size_t)(mp * 2) * 128 * 128;
    const float* A1 = (k < 64)  ? eprow + (size_t)k * 128 : prep_W + (size_t)(k - 64) * 128;
    const float* B1 = ((k < 64)  ? We_self : We_neigh) + (size_t)(mp * 2) * 128 * 128;
    __shared__ float sA0[2][128], sA1[2][128];
    sA0[half][n] = A0[n]; sA1[half][n] = A1[n];
    __syncthreads();
    float acc0 = 0.f, acc1 = 0.f;
#pragma unroll 8
    for (int j = 0; j < 128; j++) {
      acc0 += sA0[half][j] * B0[j * 128 + n];
      acc1 += sA1[half][j] * B1[j * 128 + n];
    }
    int ks = k >> 5, l4 = (k >> 3) & 3, e = k & 7;
    W0F[(((size_t)(mp * 6 + ks) * 4 + l4) * 128 + n) * 8 + e] = f2bf(acc0);
    W1F[(((size_t)(mp * 6 + ks) * 4 + l4) * 128 + n) * 8 + e] = f2bf(acc1);
  } else if (bx < 256) {
    int half = threadIdx.x >> 7, n = threadIdx.x & 127;
    int w2 = (bx - 192) * 2 + half;   // [0,128)
    int mp = w2 >> 6;
    int kb = (w2 & 63) * 4;
#pragma unroll
    for (int kk = 0; kk < 4; kk++) {
      int k = kb + kk;
      float v = (k < 128) ? Wn_self[(((size_t)(mp * 2) + 1) * 128 + k) * 128 + n]
                          : Wn_neigh[(((size_t)(mp * 2) + 1) * 128 + (k - 128)) * 128 + n];
      int ks = k >> 5, l4 = (k >> 3) & 3, e = k & 7;
      W2F[(((size_t)(mp * 8 + ks) * 4 + l4) * 128 + n) * 8 + e] = f2bf(v);
    }
  } else {
    const int n = NN * DF / 8;
    for (int i = (bx - 256) * 256 + threadIdx.x; i < n; i += 2048 * 256) {
      const float4* s = (const float4*)(feats + (size_t)i * 8);
      float4 v0 = s[0], v1 = s[1];
      *(bf16x8*)(fb + (size_t)i * 8) = pack8(v0, v1);
    }
  }
}

// ---------- C: gathered GEMM1 + relu + pool, fused ebar + feats copy ----------
// r4-winning structure: one seed per wave, 4 seeds/block, full W (48KB) staged
// once into LDS, 2 barriers total. (256,3) is non-binding for VGPR (~80) --
// forcing higher occupancy (r5/r7) only produced spills; W-half staging (r7/r8)
// cost 10-27us vs this. G2c output is compact [2][4096][128] (mh1 only).
__global__ __launch_bounds__(256, 3) void gemm1_pool(
    const int* __restrict__ ids,
    const int* __restrict__ n2e0, const int* __restrict__ n2e1,
    const int* __restrict__ adj0, const int* __restrict__ adj1,
    const float* __restrict__ ee0, const float* __restrict__ ee1,
    const unsigned short* __restrict__ featsbf,
    const unsigned short* __restrict__ W1F,
    unsigned short* __restrict__ G0, unsigned short* __restrict__ G2c) {
  __shared__ unsigned short sW[6 * 4 * 128 * 8];   // 49152 B
  int wg   = blockIdx.x;     // 2 * 1024
  int mp   = wg >> 10;
  int tile = wg & 1023;
  int wave = threadIdx.x >> 6, lane = threadIdx.x & 63;
  int l15 = lane & 15, l4 = lane >> 4;
  int seed = tile * 4 + wave;

  const int*   n2e = mp ? n2e1 : n2e0;
  const int*   adj = mp ? adj1 : adj0;
  const float* ee  = mp ? ee1 : ee0;

  // stage W fragments (L2-resident) -> LDS, coalesced
  {
    const uint4* src = (const uint4*)(W1F + (size_t)mp * 24576);
    uint4* dst = (uint4*)sW;
    for (int u = threadIdx.x; u < 3072; u += 256) dst[u] = src[u];
  }

  // index chain (longest dependent path)
  int id = ids[seed];   // wave-uniform
  int eidA = n2e[(size_t)id * S + l15];
  int eidB = n2e[(size_t)id * S + 16 + l15];
  int2 abA = *(const int2*)(adj + (size_t)eidA * 2);
  int2 abB = *(const int2*)(adj + (size_t)eidB * 2);
  int eids[2] = {eidA, eidB};
  int2 abx[2] = {abA, abB};

  bf16x8 a[2][6];          // A fragments: [mi][ks]
  float esum[2][8];        // f32 partial sums of raw ee (for ebar)
#pragma unroll
  for (int j = 0; j < 8; j++) { esum[0][j] = 0.f; esum[1][j] = 0.f; }

#pragma unroll
  for (int mi = 0; mi < 2; mi++) {
    const float* ep = ee + (size_t)eids[mi] * DE + l4 * 8;
#pragma unroll
    for (int ks = 0; ks < 2; ks++) {
      float4 v0 = *(const float4*)(ep + ks * 32);
      float4 v1 = *(const float4*)(ep + ks * 32 + 4);
      esum[ks][0] += v0.x; esum[ks][1] += v0.y; esum[ks][2] += v0.z; esum[ks][3] += v0.w;
      esum[ks][4] += v1.x; esum[ks][5] += v1.y; esum[ks][6] += v1.z; esum[ks][7] += v1.w;
      a[mi][ks] = pack8(v0, v1);
    }
    const unsigned short* fa = featsbf + (size_t)abx[mi].x * DF + l4 * 8;
    const unsigned short* fb = featsbf + (size_t)abx[mi].y * DF + l4 * 8;
#pragma unroll
    for (int ks = 2; ks < 6; ks++) {
      int off = (ks - 2) * 32;
      bf16x8 va = *(const bf16x8*)(fa + off);
      bf16x8 vb = *(const bf16x8*)(fb + off);
      a[mi][ks] = avg8(va, vb);
    }
  }

  __syncthreads();   // sW visible

  // MFMA: M=32 (2 mi), N=128 in two 64-col passes, K=192 (6 ks)
  unsigned short* G2row = G2c + ((size_t)(mp * B + seed)) * 128;
  for (int pass = 0; pass < 2; pass++) {
    f32x4 acc[2][4] = {};
#pragma unroll
    for (int ks = 0; ks < 6; ks++) {
      bf16x8 bw[4];
#pragma unroll
      for (int ni = 0; ni < 4; ni++) {
        int c = pass * 64 + ni * 16 + l15;
        bw[ni] = *(const bf16x8*)(sW + ((size_t)((ks * 4 + l4) * 128 + c)) * 8);
      }
#pragma unroll
      for (int mi = 0; mi < 2; mi++)
#pragma unroll
        for (int ni = 0; ni < 4; ni++)
          acc[mi][ni] = __builtin_amdgcn_mfma_f32_16x16x32_bf16(a[mi][ks], bw[ni], acc[mi][ni], 0, 0, 0);
    }
    // relu + mean over 32 edge rows
#pragma unroll
    for (int ni = 0; ni < 4; ni++) {
      float ssum = 0.f;
#pragma unroll
      for (int mi = 0; mi < 2; mi++)
#pragma unroll
        for (int q = 0; q < 4; q++)
          ssum += fmaxf(acc[mi][ni][q], 0.f);
      ssum += __shfl_xor(ssum, 16);
      ssum += __shfl_xor(ssum, 32);
      if (l4 == 0) G2row[pass * 64 + ni * 16 + l15] = f2bf(ssum * (1.f / 32.f));
    }
  }

  // ebar: butterfly over the 16 l15 lanes
#pragma unroll
  for (int ks = 0; ks < 2; ks++)
#pragma unroll
    for (int j = 0; j < 8; j++) {
      float v = esum[ks][j];
      v += __shfl_xor(v, 1); v += __shfl_xor(v, 2);
      v += __shfl_xor(v, 4); v += __shfl_xor(v, 8);
      esum[ks][j] = v;
    }
  unsigned short* G0row = G0 + ((size_t)(mp * B + seed)) * K0;
  if (l15 == 0) {
#pragma unroll
    for (int ks = 0; ks < 2; ks++) {
      float4 lo, hi;
      lo.x = esum[ks][0] * (1.f / 32.f); lo.y = esum[ks][1] * (1.f / 32.f);
      lo.z = esum[ks][2] * (1.f / 32.f); lo.w = esum[ks][3] * (1.f / 32.f);
      hi.x = esum[ks][4] * (1.f / 32.f); hi.y = esum[ks][5] * (1.f / 32.f);
      hi.z = esum[ks][6] * (1.f / 32.f); hi.w = esum[ks][7] * (1.f / 32.f);
      *(bf16x8*)(G0row + 128 + ks * 32 + l4 * 8) = pack8(lo, hi);
    }
  }
  // feats copy: G0[seed][0:128] = featsbf[id] (one coalesced 256B store/wave)
  ((unsigned int*)G0row)[lane] = ((const unsigned int*)(featsbf + (size_t)id * DF))[lane];
}

// ---------- D+F fused: h0 = relu(G0@W0) -> out[:,0:128]; then
//            out[:,128:256] = relu([h0|mh1]@W2), h0 routed via LDS ----------
__global__ __launch_bounds__(256) void fused_dense(
    const unsigned short* __restrict__ G0,   // [2][4096][192] bf16
    const unsigned short* __restrict__ G2c,  // [2][4096][128] bf16 (mh1)
    const unsigned short* __restrict__ W0F,  // [mp][6][4][128][8]
    const unsigned short* __restrict__ W2F,  // [mp][8][4][128][8]
    float* __restrict__ out) {               // [2][4096][256] f32
  __shared__ unsigned short Gt0[32 * 200];   // 12800 B
  __shared__ unsigned short Gt2[32 * 264];   // 16896 B
  int wg   = blockIdx.x;       // 2 * 128
  int mp   = wg >> 7;
  int tile = wg & 127;
  const unsigned short* G0src = G0 + ((size_t)mp * B + tile * 32) * K0;
  const unsigned short* G2src = G2c + ((size_t)mp * B + tile * 32) * 128;
  const unsigned short* W0f = W0F + (size_t)mp * 6 * 4 * 128 * 8;
  const unsigned short* W2f = W2F + (size_t)mp * 8 * 4 * 128 * 8;
  int t = threadIdx.x;

  // stage G0 tile (32x192) and mh1 tile (32x128 -> Gt2 cols 128:256)
  for (int u = t; u < 768; u += 256) {
    int row = u / 24, col = u % 24;
    *(uint4*)(&Gt0[row * 200 + col * 8]) = *(const uint4*)(G0src + (size_t)row * K0 + col * 8);
  }
  for (int u = t; u < 512; u += 256) {
    int row = u >> 4, col = u & 15;
    *(uint4*)(&Gt2[row * 264 + 128 + col * 8]) = *(const uint4*)(G2src + (size_t)row * 128 + col * 8);
  }
  __syncthreads();

  int wave = t >> 6, lane = t & 63;
  int l15 = lane & 15, l4 = lane >> 4;

  // GEMM0: h0 = relu([f|ebar] @ W0), K=192
  f32x4 acc[2][2] = {};
#pragma unroll
  for (int ks = 0; ks < 6; ks++) {
    bf16x8 af[2], bw[2];
#pragma unroll
    for (int mi = 0; mi < 2; mi++)
      af[mi] = *(const bf16x8*)(&Gt0[(mi * 16 + l15) * 200 + ks * 32 + l4 * 8]);
#pragma unroll
    for (int ni = 0; ni < 2; ni++) {
      int c = wave * 32 + ni * 16 + l15;
      bw[ni] = *(const bf16x8*)(W0f + ((size_t)((ks * 4 + l4) * 128 + c)) * 8);
    }
#pragma unroll
    for (int mi = 0; mi < 2; mi++)
#pragma unroll
      for (int ni = 0; ni < 2; ni++)
        acc[mi][ni] = __builtin_amdgcn_mfma_f32_16x16x32_bf16(af[mi], bw[ni], acc[mi][ni], 0, 0, 0);
  }
  // h0: relu -> out cols 0:128 (f32) + Gt2 cols 0:128 (bf16)
#pragma unroll
  for (int mi = 0; mi < 2; mi++)
#pragma unroll
    for (int ni = 0; ni < 2; ni++)
#pragma unroll
      for (int q = 0; q < 4; q++) {
        int row = mi * 16 + l4 * 4 + q;
        int col = wave * 32 + ni * 16 + l15;
        float v = fmaxf(acc[mi][ni][q], 0.f);
        size_t r = (size_t)(mp * B) + tile * 32 + row;
        out[r * 256 + col] = v;
        Gt2[row * 264 + col] = f2bf(v);
      }
  __syncthreads();

  // GEMM2: out[:,128:256] = relu([h0|mh1] @ W2), K=256
  f32x4 acc2[2][2] = {};
#pragma unroll
  for (int ks = 0; ks < 8; ks++) {
    bf16x8 af[2], bw[2];
#pragma unroll
    for (int mi = 0; mi < 2; mi++)
      af[mi] = *(const bf16x8*)(&Gt2[(mi * 16 + l15) * 264 + ks * 32 + l4 * 8]);
#pragma unroll
    for (int ni = 0; ni < 2; ni++) {
      int c = wave * 32 + ni * 16 + l15;
      bw[ni] = *(const bf16x8*)(W2f + ((size_t)((ks * 4 + l4) * 128 + c)) * 8);
    }
#pragma unroll
    for (int mi = 0; mi < 2; mi++)
#pragma unroll
      for (int ni = 0; ni < 2; ni++)
        acc2[mi][ni] = __builtin_amdgcn_mfma_f32_16x16x32_bf16(af[mi], bw[ni], acc2[mi][ni], 0, 0, 0);
  }
#pragma unroll
  for (int mi = 0; mi < 2; mi++)
#pragma unroll
    for (int ni = 0; ni < 2; ni++)
#pragma unroll
      for (int q = 0; q < 4; q++) {
        int row = mi * 16 + l4 * 4 + q;
        int col = wave * 32 + ni * 16 + l15;
        float v = fmaxf(acc2[mi][ni][q], 0.f);
        size_t r = (size_t)(mp * B) + tile * 32 + row;
        out[r * 256 + 128 + col] = v;
      }
}

extern "C" void kernel_launch(void* const* d_in, const int* in_sizes, int n_in,
                              void* d_out, int out_size, void* d_ws, size_t ws_size,
                              hipStream_t stream) {
  (void)in_sizes; (void)n_in; (void)out_size; (void)ws_size;
  const int*   ids    = (const int*)d_in[0];
  const float* feats  = (const float*)d_in[1];
  const int*   n2e0   = (const int*)d_in[2];
  const int*   n2e1   = (const int*)d_in[3];
  const int*   adj0   = (const int*)d_in[4];
  const int*   adj1   = (const int*)d_in[5];
  const float* ee0    = (const float*)d_in[6];
  const float* ee1    = (const float*)d_in[7];
  const float* prep_W = (const float*)d_in[8];
  const float* eprep  = (const float*)d_in[9];
  const float* WnS    = (const float*)d_in[10];
  const float* WnN    = (const float*)d_in[11];
  const float* WeS    = (const float*)d_in[12];
  const float* WeN    = (const float*)d_in[13];
  float* out = (float*)d_out;

  char* ws = (char*)d_ws;
  unsigned short* featsbf = (unsigned short*)(ws);                  // 25,600,000 B
  unsigned short* W0F = (unsigned short*)(ws + 25600000);           // 98304 B
  unsigned short* W1F = (unsigned short*)(ws + 25698304);           // 98304 B
  unsigned short* W2F = (unsigned short*)(ws + 25796608);           // 131072 B
  unsigned short* G0  = (unsigned short*)(ws + 25927680);           // 3,145,728 B
  unsigned short* G2c = (unsigned short*)(ws + 29073408);           // 2,097,152 B

  hipLaunchKernelGGL(prep, dim3(2304), dim3(256), 0, stream,
                     prep_W, eprep, WnS, WnN, WeS, WeN, feats, W0F, W1F, W2F, featsbf);
  hipLaunchKernelGGL(gemm1_pool, dim3(2 * 1024), dim3(256), 0, stream,
                     ids, n2e0, n2e1, adj0, adj1, ee0, ee1, featsbf, W1F, G0, G2c);
  hipLaunchKernelGGL(fused_dense, dim3(2 * 128), dim3(256), 0, stream,
                     G0, G2c, W0F, W2F, out);
}

// Round 11
// 72.828 us; speedup vs baseline: 1.3291x; 1.0229x over previous
//
#include <hip/hip_runtime.h>
#include <hip/hip_bf16.h>

#define NN 100000
#define NE 400000
#define S  32
#define B  4096
#define DF 128
#define DE 64
#define D  128
#define K1 192   // gemm1 LHS row: [e(64), fbar(128)]
#define K0 192   // gemm0 LHS row: [f(128), ebar(64)]
#define K2 256   // gemm2 LHS row: [h0(128), mh1(128)]

typedef __attribute__((ext_vector_type(8))) short bf16x8;
typedef __attribute__((ext_vector_type(4))) float f32x4;

__device__ __forceinline__ unsigned short f2bf(float x) {
  union { float f; unsigned int u; } v; v.f = x;
  unsigned int r = (v.u + 0x7FFFu + ((v.u >> 16) & 1u)) >> 16;
  return (unsigned short)r;
}

__device__ __forceinline__ float bf2f(unsigned short s) {
  union { float f; unsigned int u; } v; v.u = ((unsigned int)s) << 16;
  return v.f;
}

// packed f32x2 -> bf16x2 (compiler emits v_cvt_pk_bf16_f32)
__device__ __forceinline__ unsigned int pk2(float lo, float hi) {
  __hip_bfloat162 h = __float22bfloat162_rn(float2{lo, hi});
  union { __hip_bfloat162 h; unsigned int u; } c; c.h = h;
  return c.u;
}

__device__ __forceinline__ bf16x8 pack8(float4 a, float4 b) {
  union { bf16x8 v; unsigned int u[4]; } c;
  c.u[0] = pk2(a.x, a.y); c.u[1] = pk2(a.z, a.w);
  c.u[2] = pk2(b.x, b.y); c.u[3] = pk2(b.z, b.w);
  return c.v;
}

// average two bf16x8 vectors (f32 math, repack)
__device__ __forceinline__ bf16x8 avg8(bf16x8 A, bf16x8 Bv) {
  union { bf16x8 v; unsigned short s[8]; } ua, ub;
  union { bf16x8 v; unsigned int u[4]; } uo;
  ua.v = A; ub.v = Bv;
#pragma unroll
  for (int p = 0; p < 4; p++) {
    float x0 = 0.5f * (bf2f(ua.s[2 * p]) + bf2f(ub.s[2 * p]));
    float x1 = 0.5f * (bf2f(ua.s[2 * p + 1]) + bf2f(ub.s[2 * p + 1]));
    uo.u[p] = pk2(x0, x1);
  }
  return uo.v;
}

// ---------- prep: fused weight-fusion + feats f32->bf16 ----------
__global__ __launch_bounds__(256) void prep(
    const float* __restrict__ prep_W, const float* __restrict__ edge_prep_W,
    const float* __restrict__ Wn_self, const float* __restrict__ Wn_neigh,
    const float* __restrict__ We_self, const float* __restrict__ We_neigh,
    const float* __restrict__ feats,
    unsigned short* __restrict__ W0F, unsigned short* __restrict__ W1F,
    unsigned short* __restrict__ W2F, unsigned short* __restrict__ fb) {
  int bx = blockIdx.x;
  if (bx < 192) {
    int half = threadIdx.x >> 7, n = threadIdx.x & 127;
    int wg = bx * 2 + half;       // [0,384)
    int mp = wg / 192, k = wg % 192;
    const float* eprow = edge_prep_W + (size_t)mp * 64 * 128;
    const float* A0 = (k < 128) ? prep_W + (size_t)k * 128 : eprow + (size_t)(k - 128) * 128;
    const float* B0 = ((k < 128) ? Wn_self : Wn_neigh) + (size_t)(mp * 2) * 128 * 128;
    const float* A1 = (k < 64)  ? eprow + (size_t)k * 128 : prep_W + (size_t)(k - 64) * 128;
    const float* B1 = ((k < 64)  ? We_self : We_neigh) + (size_t)(mp * 2) * 128 * 128;
    __shared__ float sA0[2][128], sA1[2][128];
    sA0[half][n] = A0[n]; sA1[half][n] = A1[n];
    __syncthreads();
    float acc0 = 0.f, acc1 = 0.f;
#pragma unroll 8
    for (int j = 0; j < 128; j++) {
      acc0 += sA0[half][j] * B0[j * 128 + n];
      acc1 += sA1[half][j] * B1[j * 128 + n];
    }
    int ks = k >> 5, l4 = (k >> 3) & 3, e = k & 7;
    W0F[(((size_t)(mp * 6 + ks) * 4 + l4) * 128 + n) * 8 + e] = f2bf(acc0);
    W1F[(((size_t)(mp * 6 + ks) * 4 + l4) * 128 + n) * 8 + e] = f2bf(acc1);
  } else if (bx < 256) {
    int half = threadIdx.x >> 7, n = threadIdx.x & 127;
    int w2 = (bx - 192) * 2 + half;   // [0,128)
    int mp = w2 >> 6;
    int kb = (w2 & 63) * 4;
#pragma unroll
    for (int kk = 0; kk < 4; kk++) {
      int k = kb + kk;
      float v = (k < 128) ? Wn_self[(((size_t)(mp * 2) + 1) * 128 + k) * 128 + n]
                          : Wn_neigh[(((size_t)(mp * 2) + 1) * 128 + (k - 128)) * 128 + n];
      int ks = k >> 5, l4 = (k >> 3) & 3, e = k & 7;
      W2F[(((size_t)(mp * 8 + ks) * 4 + l4) * 128 + n) * 8 + e] = f2bf(v);
    }
  } else {
    const int n = NN * DF / 8;
    for (int i = (bx - 256) * 256 + threadIdx.x; i < n; i += 2048 * 256) {
      const float4* s = (const float4*)(feats + (size_t)i * 8);
      float4 v0 = s[0], v1 = s[1];
      *(bf16x8*)(fb + (size_t)i * 8) = pack8(v0, v1);
    }
  }
}

// ---------- C: gathered GEMM1 + relu + pool + ebar ----------
// One seed per wave, 8 seeds/block (512 thr), full W (48KB) staged once.
// N processed in FOUR 32-col passes (acc 16 + bw 8 regs) so the live set
// fits the (512,4) cap of 64 VGPRs -> 8 waves/SIMD possible; LDS caps at
// 3 blocks * 8 = 24 waves/CU. ebar derived post-hoc from bf16 A-fragments.
__global__ __launch_bounds__(512, 4) void gemm1_pool(
    const int* __restrict__ ids,
    const int* __restrict__ n2e0, const int* __restrict__ n2e1,
    const int* __restrict__ adj0, const int* __restrict__ adj1,
    const float* __restrict__ ee0, const float* __restrict__ ee1,
    const unsigned short* __restrict__ featsbf,
    const unsigned short* __restrict__ W1F,
    unsigned short* __restrict__ Geb, unsigned short* __restrict__ G2c) {
  __shared__ unsigned short sW[6 * 4 * 128 * 8];   // 49152 B
  int wg   = blockIdx.x;     // 2 * 512
  int mp   = wg >> 9;
  int tile = wg & 511;
  int wave = threadIdx.x >> 6, lane = threadIdx.x & 63;
  int l15 = lane & 15, l4 = lane >> 4;
  int seed = tile * 8 + wave;

  const int*   n2e = mp ? n2e1 : n2e0;
  const int*   adj = mp ? adj1 : adj0;
  const float* ee  = mp ? ee1 : ee0;

  // stage W fragments (L2-resident) -> LDS, coalesced
  {
    const uint4* src = (const uint4*)(W1F + (size_t)mp * 24576);
    uint4* dst = (uint4*)sW;
    for (int u = threadIdx.x; u < 3072; u += 512) dst[u] = src[u];
  }

  // index chain (longest dependent path)
  int id = ids[seed];   // wave-uniform
  int eidA = n2e[(size_t)id * S + l15];
  int eidB = n2e[(size_t)id * S + 16 + l15];
  int2 abA = *(const int2*)(adj + (size_t)eidA * 2);
  int2 abB = *(const int2*)(adj + (size_t)eidB * 2);
  int eids[2] = {eidA, eidB};
  int2 abx[2] = {abA, abB};

  bf16x8 a[2][6];          // A fragments: [mi][ks]
#pragma unroll
  for (int mi = 0; mi < 2; mi++) {
    const float* ep = ee + (size_t)eids[mi] * DE + l4 * 8;
#pragma unroll
    for (int ks = 0; ks < 2; ks++) {
      float4 v0 = *(const float4*)(ep + ks * 32);
      float4 v1 = *(const float4*)(ep + ks * 32 + 4);
      a[mi][ks] = pack8(v0, v1);
    }
    const unsigned short* fa = featsbf + (size_t)abx[mi].x * DF + l4 * 8;
    const unsigned short* fb = featsbf + (size_t)abx[mi].y * DF + l4 * 8;
#pragma unroll
    for (int ks = 2; ks < 6; ks++) {
      int off = (ks - 2) * 32;
      bf16x8 va = *(const bf16x8*)(fa + off);
      bf16x8 vb = *(const bf16x8*)(fb + off);
      a[mi][ks] = avg8(va, vb);
    }
  }

  __syncthreads();   // sW visible

  // MFMA: M=32 (2 mi), N=128 in four 32-col passes, K=192 (6 ks)
  unsigned short* G2row = G2c + ((size_t)(mp * B + seed)) * 128;
#pragma unroll 1
  for (int pass = 0; pass < 4; pass++) {
    f32x4 acc[2][2] = {};
#pragma unroll
    for (int ks = 0; ks < 6; ks++) {
      bf16x8 bw[2];
#pragma unroll
      for (int ni = 0; ni < 2; ni++) {
        int c = pass * 32 + ni * 16 + l15;
        bw[ni] = *(const bf16x8*)(sW + ((size_t)((ks * 4 + l4) * 128 + c)) * 8);
      }
#pragma unroll
      for (int mi = 0; mi < 2; mi++)
#pragma unroll
        for (int ni = 0; ni < 2; ni++)
          acc[mi][ni] = __builtin_amdgcn_mfma_f32_16x16x32_bf16(a[mi][ks], bw[ni], acc[mi][ni], 0, 0, 0);
    }
    // relu + mean over 32 edge rows
#pragma unroll
    for (int ni = 0; ni < 2; ni++) {
      float ssum = 0.f;
#pragma unroll
      for (int mi = 0; mi < 2; mi++)
#pragma unroll
        for (int q = 0; q < 4; q++)
          ssum += fmaxf(acc[mi][ni][q], 0.f);
      ssum += __shfl_xor(ssum, 16);
      ssum += __shfl_xor(ssum, 32);
      if (l4 == 0) G2row[pass * 32 + ni * 16 + l15] = f2bf(ssum * (1.f / 32.f));
    }
  }

  // ebar: derive from bf16 A-fragments (epilogue-only registers),
  // butterfly over the 16 l15 lanes -> mean over 32 edges
  unsigned short* Gerow = Geb + ((size_t)(mp * B + seed)) * 64;
#pragma unroll
  for (int ks = 0; ks < 2; ks++) {
    union { bf16x8 v; unsigned short s[8]; } u0, u1;
    u0.v = a[0][ks]; u1.v = a[1][ks];
    float es[8];
#pragma unroll
    for (int j = 0; j < 8; j++) {
      float v = bf2f(u0.s[j]) + bf2f(u1.s[j]);
      v += __shfl_xor(v, 1); v += __shfl_xor(v, 2);
      v += __shfl_xor(v, 4); v += __shfl_xor(v, 8);
      es[j] = v * (1.f / 32.f);
    }
    if (l15 == 0) {
      float4 lo = {es[0], es[1], es[2], es[3]};
      float4 hi = {es[4], es[5], es[6], es[7]};
      *(bf16x8*)(Gerow + ks * 32 + l4 * 8) = pack8(lo, hi);
    }
  }
}

// ---------- D+F fused: h0 = relu([feats[id]|ebar]@W0) -> out[:,0:128];
//            out[:,128:256] = relu([h0|mh1]@W2), h0 routed via LDS ----------
__global__ __launch_bounds__(256) void fused_dense(
    const int* __restrict__ ids,
    const unsigned short* __restrict__ featsbf,  // [NN][128] bf16
    const unsigned short* __restrict__ Geb,      // [2][4096][64] bf16 (ebar)
    const unsigned short* __restrict__ G2c,      // [2][4096][128] bf16 (mh1)
    const unsigned short* __restrict__ W0F,      // [mp][6][4][128][8]
    const unsigned short* __restrict__ W2F,      // [mp][8][4][128][8]
    float* __restrict__ out) {                   // [2][4096][256] f32
  __shared__ unsigned short Gt0[32 * 200];   // 12800 B
  __shared__ unsigned short Gt2[32 * 264];   // 16896 B
  int wg   = blockIdx.x;       // 2 * 128
  int mp   = wg >> 7;
  int tile = wg & 127;
  const unsigned short* G2src = G2c + ((size_t)mp * B + tile * 32) * 128;
  const unsigned short* W0f = W0F + (size_t)mp * 6 * 4 * 128 * 8;
  const unsigned short* W2f = W2F + (size_t)mp * 8 * 4 * 128 * 8;
  int t = threadIdx.x;

  // stage Gt0: 24 uint4 chunks/row = feats[id] (16 chunks) + ebar (8 chunks)
  for (int u = t; u < 768; u += 256) {
    int row = u / 24, col = u % 24;
    if (col < 16) {
      int id = ids[tile * 32 + row];
      *(uint4*)(&Gt0[row * 200 + col * 8]) =
          *(const uint4*)(featsbf + (size_t)id * DF + col * 8);
    } else {
      *(uint4*)(&Gt0[row * 200 + col * 8]) =
          *(const uint4*)(Geb + ((size_t)(mp * B) + tile * 32 + row) * 64 + (col - 16) * 8);
    }
  }
  // stage mh1 tile (32x128 -> Gt2 cols 128:256)
  for (int u = t; u < 512; u += 256) {
    int row = u >> 4, col = u & 15;
    *(uint4*)(&Gt2[row * 264 + 128 + col * 8]) = *(const uint4*)(G2src + (size_t)row * 128 + col * 8);
  }
  __syncthreads();

  int wave = t >> 6, lane = t & 63;
  int l15 = lane & 15, l4 = lane >> 4;

  // GEMM0: h0 = relu([f|ebar] @ W0), K=192
  f32x4 acc[2][2] = {};
#pragma unroll
  for (int ks = 0; ks < 6; ks++) {
    bf16x8 af[2], bw[2];
#pragma unroll
    for (int mi = 0; mi < 2; mi++)
      af[mi] = *(const bf16x8*)(&Gt0[(mi * 16 + l15) * 200 + ks * 32 + l4 * 8]);
#pragma unroll
    for (int ni = 0; ni < 2; ni++) {
      int c = wave * 32 + ni * 16 + l15;
      bw[ni] = *(const bf16x8*)(W0f + ((size_t)((ks * 4 + l4) * 128 + c)) * 8);
    }
#pragma unroll
    for (int mi = 0; mi < 2; mi++)
#pragma unroll
      for (int ni = 0; ni < 2; ni++)
        acc[mi][ni] = __builtin_amdgcn_mfma_f32_16x16x32_bf16(af[mi], bw[ni], acc[mi][ni], 0, 0, 0);
  }
  // h0: relu -> out cols 0:128 (f32) + Gt2 cols 0:128 (bf16)
#pragma unroll
  for (int mi = 0; mi < 2; mi++)
#pragma unroll
    for (int ni = 0; ni < 2; ni++)
#pragma unroll
      for (int q = 0; q < 4; q++) {
        int row = mi * 16 + l4 * 4 + q;
        int col = wave * 32 + ni * 16 + l15;
        float v = fmaxf(acc[mi][ni][q], 0.f);
        size_t r = (size_t)(mp * B) + tile * 32 + row;
        out[r * 256 + col] = v;
        Gt2[row * 264 + col] = f2bf(v);
      }
  __syncthreads();

  // GEMM2: out[:,128:256] = relu([h0|mh1] @ W2), K=256
  f32x4 acc2[2][2] = {};
#pragma unroll
  for (int ks = 0; ks < 8; ks++) {
    bf16x8 af[2], bw[2];
#pragma unroll
    for (int mi = 0; mi < 2; mi++)
      af[mi] = *(const bf16x8*)(&Gt2[(mi * 16 + l15) * 264 + ks * 32 + l4 * 8]);
#pragma unroll
    for (int ni = 0; ni < 2; ni++) {
      int c = wave * 32 + ni * 16 + l15;
      bw[ni] = *(const bf16x8*)(W2f + ((size_t)((ks * 4 + l4) * 128 + c)) * 8);
    }
#pragma unroll
    for (int mi = 0; mi < 2; mi++)
#pragma unroll
      for (int ni = 0; ni < 2; ni++)
        acc2[mi][ni] = __builtin_amdgcn_mfma_f32_16x16x32_bf16(af[mi], bw[ni], acc2[mi][ni], 0, 0, 0);
  }
#pragma unroll
  for (int mi = 0; mi < 2; mi++)
#pragma unroll
    for (int ni = 0; ni < 2; ni++)
#pragma unroll
      for (int q = 0; q < 4; q++) {
        int row = mi * 16 + l4 * 4 + q;
        int col = wave * 32 + ni * 16 + l15;
        float v = fmaxf(acc2[mi][ni][q], 0.f);
        size_t r = (size_t)(mp * B) + tile * 32 + row;
        out[r * 256 + 128 + col] = v;
      }
}

extern "C" void kernel_launch(void* const* d_in, const int* in_sizes, int n_in,
                              void* d_out, int out_size, void* d_ws, size_t ws_size,
                              hipStream_t stream) {
  (void)in_sizes; (void)n_in; (void)out_size; (void)ws_size;
  const int*   ids    = (const int*)d_in[0];
  const float* feats  = (const float*)d_in[1];
  const int*   n2e0   = (const int*)d_in[2];
  const int*   n2e1   = (const int*)d_in[3];
  const int*   adj0   = (const int*)d_in[4];
  const int*   adj1   = (const int*)d_in[5];
  const float* ee0    = (const float*)d_in[6];
  const float* ee1    = (const float*)d_in[7];
  const float* prep_W = (const float*)d_in[8];
  const float* eprep  = (const float*)d_in[9];
  const float* WnS    = (const float*)d_in[10];
  const float* WnN    = (const float*)d_in[11];
  const float* WeS    = (const float*)d_in[12];
  const float* WeN    = (const float*)d_in[13];
  float* out = (float*)d_out;

  char* ws = (char*)d_ws;
  unsigned short* featsbf = (unsigned short*)(ws);                  // 25,600,000 B
  unsigned short* W0F = (unsigned short*)(ws + 25600000);           // 98304 B
  unsigned short* W1F = (unsigned short*)(ws + 25698304);           // 98304 B
  unsigned short* W2F = (unsigned short*)(ws + 25796608);           // 131072 B
  unsigned short* Geb = (unsigned short*)(ws + 25927680);           // 1,048,576 B
  unsigned short* G2c = (unsigned short*)(ws + 26976256);           // 2,097,152 B

  hipLaunchKernelGGL(prep, dim3(2304), dim3(256), 0, stream,
                     prep_W, eprep, WnS, WnN, WeS, WeN, feats, W0F, W1F, W2F, featsbf);
  hipLaunchKernelGGL(gemm1_pool, dim3(2 * 512), dim3(512), 0, stream,
                     ids, n2e0, n2e1, adj0, adj1, ee0, ee1, featsbf, W1F, Geb, G2c);
  hipLaunchKernelGGL(fused_dense, dim3(2 * 128), dim3(256), 0, stream,
                     ids, featsbf, Geb, G2c, W0F, W2F, out);
}